// Round 6
// baseline (629.392 us; speedup 1.0000x reference)
//
#include <hip/hip_runtime.h>
#include <math.h>

#define SCALING_F 0.46211715726000974f   // tanh(0.5)
#define MAXNORM_F 0.996f                 // 1 - BALL_EPS
#define MINNORM_F 1e-15f
#define BN_EPS_F  1e-5f

// reduce over the 16-lane group holding one row
__device__ __forceinline__ float rsum16(float v) {
  v += __shfl_xor(v, 1, 64);
  v += __shfl_xor(v, 2, 64);
  v += __shfl_xor(v, 4, 64);
  v += __shfl_xor(v, 8, 64);
  return v;
}

// six independent 16-lane reductions, pipelined
__device__ __forceinline__ void rsum16x6(float& a, float& b, float& c,
                                         float& d, float& e, float& f) {
#pragma unroll
  for (int o = 1; o <= 8; o <<= 1) {
    a += __shfl_xor(a, o, 64);
    b += __shfl_xor(b, o, 64);
    c += __shfl_xor(c, o, 64);
    d += __shfl_xor(d, o, 64);
    e += __shfl_xor(e, o, 64);
    f += __shfl_xor(f, o, 64);
  }
}

// ---------------------------------------------------------------------------
// mm0: X = relu(x_in @ W0 + b0)  (K=128), fused proj epilogue.
// 16-row tile, 256 threads: thread = (row = tid>>4, cols c0..c0+3).
// ---------------------------------------------------------------------------
__global__ __launch_bounds__(256) void k_mm0(
    const float* __restrict__ A, const float* __restrict__ B,
    const float* __restrict__ bias, float* __restrict__ X,
    float* __restrict__ Z, int M, int K)
{
  __shared__ float As[16][65];
  __shared__ float Bs[64][64];
  const int tid   = threadIdx.x;
  const int c0    = (tid & 15) * 4;
  const int row_l = tid >> 4;
  const int rblk  = blockIdx.x * 16;
  const int row   = rblk + row_l;
  float acc[4] = {0.f, 0.f, 0.f, 0.f};

  for (int kk = 0; kk < K; kk += 64) {
#pragma unroll
    for (int j = 0; j < 4; ++j) {
      int f = j * 256 + tid;
      int bk = f >> 4, bc = (f & 15) * 4;
      *(float4*)&Bs[bk][bc] = *(const float4*)&B[(size_t)(kk + bk) * 64 + bc];
    }
    {
      int ar = tid >> 4, ac = (tid & 15) * 4;
      int r = rblk + ar;
      float4 av = make_float4(0.f, 0.f, 0.f, 0.f);
      if (r < M) av = *(const float4*)&A[(size_t)r * K + kk + ac];
      As[ar][ac + 0] = av.x;
      As[ar][ac + 1] = av.y;
      As[ar][ac + 2] = av.z;
      As[ar][ac + 3] = av.w;
    }
    __syncthreads();
#pragma unroll 16
    for (int k = 0; k < 64; ++k) {
      float4 b4 = *(float4*)&Bs[k][c0];
      float a = As[row_l][k];
      acc[0] = fmaf(a, b4.x, acc[0]);
      acc[1] = fmaf(a, b4.y, acc[1]);
      acc[2] = fmaf(a, b4.z, acc[2]);
      acc[3] = fmaf(a, b4.w, acc[3]);
    }
    __syncthreads();
  }

  float v0 = fmaxf(acc[0] + bias[c0+0], 0.f);
  float v1 = fmaxf(acc[1] + bias[c0+1], 0.f);
  float v2 = fmaxf(acc[2] + bias[c0+2], 0.f);
  float v3 = fmaxf(acc[3] + bias[c0+3], 0.f);
  if (row < M)
    *(float4*)&X[(size_t)row * 64 + c0] = make_float4(v0, v1, v2, v3);
  float sx = rsum16(v0*v0 + v1*v1 + v2*v2 + v3*v3);
  float norm = fmaxf(sqrtf(sx), MINNORM_F);
  float s = ((norm > MAXNORM_F) ? (MAXNORM_F / norm) : 1.0f) * SCALING_F;
  if (row < M)
    *(float4*)&Z[(size_t)row * 64 + c0] = make_float4(v0*s, v1*s, v2*s, v3*s);
}

// ---------------------------------------------------------------------------
// K1: h = relu((x[r] + sum_nb x[nb]) @ W1 + b1), fused BN statistics.
// 16-row tile; 4 waves each gather 4 rows into As.
// ---------------------------------------------------------------------------
__global__ __launch_bounds__(256) void k_layer1(
    const float* __restrict__ x, const int* __restrict__ rowptr,
    const int* __restrict__ csr, const float* __restrict__ B,
    const float* __restrict__ bias, float* __restrict__ h,
    float* __restrict__ gstat, int M)
{
  __shared__ float As[16][65];
  __shared__ float Bs[64][64];
  const int tid   = threadIdx.x;
  const int c0    = (tid & 15) * 4;
  const int row_l = tid >> 4;
  const int rblk  = blockIdx.x * 16;
  const int wv    = tid >> 6;
  const int lane  = tid & 63;

#pragma unroll
  for (int j = 0; j < 4; ++j) {
    int f = j * 256 + tid;
    int bk = f >> 4, bc = (f & 15) * 4;
    *(float4*)&Bs[bk][bc] = *(const float4*)&B[(size_t)bk * 64 + bc];
  }
#pragma unroll
  for (int rr = 0; rr < 4; ++rr) {
    int lr = wv * 4 + rr;
    int r  = rblk + lr;
    float acc = 0.f;
    if (r < M) {
      acc = x[(size_t)r * 64 + lane];
      int beg = rowptr[r], end = rowptr[r + 1];
      int j = beg;
      for (; j + 8 <= end; j += 8) {
        int n0 = csr[j+0], n1 = csr[j+1], n2 = csr[j+2], n3 = csr[j+3];
        int n4 = csr[j+4], n5 = csr[j+5], n6 = csr[j+6], n7 = csr[j+7];
        float v0 = x[(size_t)n0*64+lane], v1 = x[(size_t)n1*64+lane];
        float v2 = x[(size_t)n2*64+lane], v3 = x[(size_t)n3*64+lane];
        float v4 = x[(size_t)n4*64+lane], v5 = x[(size_t)n5*64+lane];
        float v6 = x[(size_t)n6*64+lane], v7 = x[(size_t)n7*64+lane];
        acc += ((v0+v1)+(v2+v3)) + ((v4+v5)+(v6+v7));
      }
      if (j + 4 <= end) {
        int n0 = csr[j+0], n1 = csr[j+1], n2 = csr[j+2], n3 = csr[j+3];
        float v0 = x[(size_t)n0*64+lane], v1 = x[(size_t)n1*64+lane];
        float v2 = x[(size_t)n2*64+lane], v3 = x[(size_t)n3*64+lane];
        acc += (v0+v1)+(v2+v3);
        j += 4;
      }
      for (; j < end; ++j) acc += x[(size_t)csr[j]*64+lane];
    }
    As[lr][lane] = acc;
  }
  __syncthreads();

  float acc[4] = {0.f, 0.f, 0.f, 0.f};
#pragma unroll 16
  for (int k = 0; k < 64; ++k) {
    float4 b4 = *(float4*)&Bs[k][c0];
    float a = As[row_l][k];
    acc[0] = fmaf(a, b4.x, acc[0]);
    acc[1] = fmaf(a, b4.y, acc[1]);
    acc[2] = fmaf(a, b4.z, acc[2]);
    acc[3] = fmaf(a, b4.w, acc[3]);
  }
  __syncthreads();   // Bs dead after this; reused as stats scratch

  const int row = rblk + row_l;
  float v0 = fmaxf(acc[0] + bias[c0+0], 0.f);
  float v1 = fmaxf(acc[1] + bias[c0+1], 0.f);
  float v2 = fmaxf(acc[2] + bias[c0+2], 0.f);
  float v3 = fmaxf(acc[3] + bias[c0+3], 0.f);
  bool valid = (row < M);
  if (valid)
    *(float4*)&h[(size_t)row * 64 + c0] = make_float4(v0, v1, v2, v3);
  if (!valid) { v0 = v1 = v2 = v3 = 0.f; }

  float* st = (float*)Bs;           // [0:1024) sums, [1024:2048) sumsq
  st[row_l * 64 + c0 + 0] = v0;
  st[row_l * 64 + c0 + 1] = v1;
  st[row_l * 64 + c0 + 2] = v2;
  st[row_l * 64 + c0 + 3] = v3;
  st[1024 + row_l * 64 + c0 + 0] = v0 * v0;
  st[1024 + row_l * 64 + c0 + 1] = v1 * v1;
  st[1024 + row_l * 64 + c0 + 2] = v2 * v2;
  st[1024 + row_l * 64 + c0 + 3] = v3 * v3;
  __syncthreads();
  if (tid < 64) {
    float a = 0.f, b = 0.f;
#pragma unroll
    for (int g2 = 0; g2 < 16; ++g2) {
      a += st[g2 * 64 + tid];
      b += st[1024 + g2 * 64 + tid];
    }
    atomicAdd(&gstat[tid], a);
    atomicAdd(&gstat[64 + tid], b);
  }
}

// ---------------------------------------------------------------------------
// K2: xn = relu(BN(h) @ W2 + b2), col63 = 0; fused hyperbolic epilogue.
// 16-row tile. BN scale/shift computed in-block from gstat.
// If Zn != null: write X and Zn. Else (last layer): logmap0 + pool.
// ---------------------------------------------------------------------------
__global__ __launch_bounds__(256) void k_layer2(
    const float* __restrict__ A, const float* __restrict__ B,
    const float* __restrict__ bias,
    const float* __restrict__ gstat, const float* __restrict__ gamma,
    const float* __restrict__ beta,
    float* __restrict__ X,
    const float* __restrict__ Zc, const float* Zp, float* Zn,
    const int* __restrict__ batch, float* __restrict__ pool, int M)
{
  __shared__ float As[16][65];
  __shared__ float Bs[64][64];
  __shared__ float scl_s[64], shf_s[64];
  const int tid   = threadIdx.x;
  const int c0    = (tid & 15) * 4;
  const int row_l = tid >> 4;
  const int rblk  = blockIdx.x * 16;
  const int row   = rblk + row_l;
  const bool valid = (row < M);

  if (tid < 64) {
    float mu  = gstat[tid] / (float)M;
    float var = gstat[64 + tid] / (float)M - mu * mu;
    float sv  = gamma[tid] / sqrtf(var + BN_EPS_F);
    scl_s[tid] = sv;
    shf_s[tid] = beta[tid] - mu * sv;
  }
  __syncthreads();

#pragma unroll
  for (int j = 0; j < 4; ++j) {
    int f = j * 256 + tid;
    int bk = f >> 4, bc = (f & 15) * 4;
    *(float4*)&Bs[bk][bc] = *(const float4*)&B[(size_t)bk * 64 + bc];
  }
  {
    int ar = tid >> 4, ac = (tid & 15) * 4;
    int r = rblk + ar;
    float4 av = make_float4(0.f, 0.f, 0.f, 0.f);
    if (r < M) av = *(const float4*)&A[(size_t)r * 64 + ac];
    As[ar][ac + 0] = fmaf(av.x, scl_s[ac+0], shf_s[ac+0]);
    As[ar][ac + 1] = fmaf(av.y, scl_s[ac+1], shf_s[ac+1]);
    As[ar][ac + 2] = fmaf(av.z, scl_s[ac+2], shf_s[ac+2]);
    As[ar][ac + 3] = fmaf(av.w, scl_s[ac+3], shf_s[ac+3]);
  }

  // prefetch zc/zp so they're in flight during staging barrier + FMA loop
  float4 zc4 = make_float4(0.f, 0.f, 0.f, 0.f);
  float4 zp4 = make_float4(0.f, 0.f, 0.f, 0.f);
  if (valid) zc4 = *(const float4*)&Zc[(size_t)row * 64 + c0];
  if (valid && Zp != nullptr) zp4 = *(const float4*)&Zp[(size_t)row * 64 + c0];
  __syncthreads();

  float acc[4] = {0.f, 0.f, 0.f, 0.f};
#pragma unroll 16
  for (int k = 0; k < 64; ++k) {
    float4 b4 = *(float4*)&Bs[k][c0];
    float a = As[row_l][k];
    acc[0] = fmaf(a, b4.x, acc[0]);
    acc[1] = fmaf(a, b4.y, acc[1]);
    acc[2] = fmaf(a, b4.z, acc[2]);
    acc[3] = fmaf(a, b4.w, acc[3]);
  }

  float xv[4];
  xv[0] = fmaxf(acc[0] + bias[c0+0], 0.f);
  xv[1] = fmaxf(acc[1] + bias[c0+1], 0.f);
  xv[2] = fmaxf(acc[2] + bias[c0+2], 0.f);
  xv[3] = fmaxf(acc[3] + bias[c0+3], 0.f);
  if (c0 == 60) xv[3] = 0.f;     // x[:, -1] = 0
  if (valid && X != nullptr)
    *(float4*)&X[(size_t)row * 64 + c0] = make_float4(xv[0],xv[1],xv[2],xv[3]);

  float zcv[4] = {zc4.x, zc4.y, zc4.z, zc4.w};
  float zpv[4] = {zp4.x, zp4.y, zp4.z, zp4.w};

  // six independent dot-product partials
  float p1 = xv[0]*xv[0] + xv[1]*xv[1] + xv[2]*xv[2] + xv[3]*xv[3];   // Σxv²
  float p2 = zcv[0]*zcv[0]+zcv[1]*zcv[1]+zcv[2]*zcv[2]+zcv[3]*zcv[3]; // Σzc²
  float p3 = zpv[0]*zpv[0]+zpv[1]*zpv[1]+zpv[2]*zpv[2]+zpv[3]*zpv[3]; // Σzp²
  float p4 = zpv[0]*zcv[0]+zpv[1]*zcv[1]+zpv[2]*zcv[2]+zpv[3]*zcv[3]; // Σzp·zc
  float p5 = zpv[0]*xv[0]+zpv[1]*xv[1]+zpv[2]*xv[2]+zpv[3]*xv[3];     // Σzp·xv
  float p6 = zcv[0]*xv[0]+zcv[1]*xv[1]+zcv[2]*xv[2]+zcv[3]*xv[3];     // Σzc·xv
  rsum16x6(p1, p2, p3, p4, p5, p6);
  float zc63 = __shfl(zcv[3], 15, 16);   // element 63 of this row
  float zp63 = __shfl(zpv[3], 15, 16);

  // ---- scalar chain (uniform within the 16-lane group) ----
  float nzc2 = fmaxf(p2, MINNORM_F);
  float icz  = 1.0f / nzc2;
  float na2  = p2 * icz * icz;           // Σa²
  float r2   = na2 - 1.0f;
  float a63  = zc63 * icz;

  float sxn = fmaxf(sqrtf(p1), MINNORM_F);
  float sc  = ((sxn > MAXNORM_F) ? (MAXNORM_F / sxn) : 1.0f) * SCALING_F;
  float Sch2   = sc * sc * p1;           // Σch²   (ch63 = 0)
  float Szp_a  = p4 * icz;               // Σzp·a
  float Sa_ch  = sc * p6 * icz;          // Σa·ch
  float Szp_ch = sc * p5;                // Σzp·ch
  float Su_a   = Szp_a - na2;            // Σ(zp−a)·a
  float Su2    = p3 - 2.0f * Szp_a + na2;
  float nu2    = fmaxf(Su2, MINNORM_F);
  float t1     = r2 / nu2;
  float Szp22  = fmaxf(t1*t1*Su2 + 2.0f*t1*Su_a + na2, 0.0f);  // Σzp2²
  float npn    = fmaxf(sqrtf(Szp22), MINNORM_F);
  float ipn    = 1.0f / npn;
  float zp2_63 = t1 * (zp63 - a63) + a63;
  float Szp2ch = t1 * (Szp_ch - Sa_ch) + Sa_ch;
  float rdc    = -ipn * Szp2ch;          // Σr·ch  (q·ch = ch63 = 0)
  float rdr    = 1.0f - 2.0f*ipn*zp2_63 + ipn*ipn*Szp22;       // Σr·r
  float m2     = 2.0f * rdc / rdr;
  float Szp2a  = t1 * Su_a + na2;        // Σzp2·a
  float Srr_a  = a63 - ipn * Szp2a;      // Σr·a
  float Sc2a   = Sa_ch - m2 * Srr_a;     // Σc2·a
  float Sc22   = Sch2 - 2.0f*m2*rdc + m2*m2*rdr;               // Σc2²
  float Sc2ma  = Sc22 - 2.0f*Sc2a + na2; // Σ(c2−a)²
  float nu22   = fmaxf(Sc2ma, MINNORM_F);
  float t2     = r2 / nu22;

  // ---- per-lane vector tail ----
  float zn[4];
#pragma unroll
  for (int i = 0; i < 4; ++i) {
    float ai  = zcv[i] * icz;
    float zp2 = t1 * (zpv[i] - ai) + ai;
    float rri = (((c0 + i) == 63) ? 1.0f : 0.0f) - ipn * zp2;
    float c2  = sc * xv[i] - m2 * rri;
    zn[i]     = t2 * (c2 - ai) + ai;
  }

  if (Zn != nullptr) {
    if (valid)
      *(float4*)&Zn[(size_t)row * 64 + c0] = make_float4(zn[0],zn[1],zn[2],zn[3]);
  } else {
    float Szn2 = fmaxf(t2*t2*Sc2ma + 2.0f*t2*(Sc2a - na2) + na2, 0.0f);
    float yn  = fmaxf(sqrtf(Szn2), MINNORM_F);
    float t   = fminf(yn, 1.0f);
    float ath = 0.5f * logf((1.0f + t) / (1.0f - t));
    float wsc = ath / yn;
    if (valid) {
      int b = batch[row];
      float* p = &pool[(size_t)b * 64 + c0];
      atomicAdd(p + 0, zn[0] * wsc);
      atomicAdd(p + 1, zn[1] * wsc);
      atomicAdd(p + 2, zn[2] * wsc);
      atomicAdd(p + 3, zn[3] * wsc);
    }
  }
}

// ---------------------------------------------------------------------------
// CSR build
// ---------------------------------------------------------------------------
__global__ __launch_bounds__(256) void k_deg(const int* __restrict__ dst, int E, int* deg) {
  int i0 = (blockIdx.x * 256 + threadIdx.x) * 4;
  if (i0 + 4 <= E) {
    int d0 = dst[i0], d1 = dst[i0+1], d2 = dst[i0+2], d3 = dst[i0+3];
    atomicAdd(&deg[d0], 1);
    atomicAdd(&deg[d1], 1);
    atomicAdd(&deg[d2], 1);
    atomicAdd(&deg[d3], 1);
  } else {
    for (int i = i0; i < E; ++i) atomicAdd(&deg[dst[i]], 1);
  }
}

__global__ __launch_bounds__(256) void k_scan1(const int* __restrict__ deg, int N,
                                               int* rowptr, int* bsum) {
  __shared__ int s[256];
  int t = threadIdx.x;
  int i = blockIdx.x * 256 + t;
  int v = (i < N) ? deg[i] : 0;
  s[t] = v;
  __syncthreads();
  for (int d = 1; d < 256; d <<= 1) {
    int add = (t >= d) ? s[t - d] : 0;
    __syncthreads();
    s[t] += add;
    __syncthreads();
  }
  if (i < N) rowptr[i] = s[t] - v;
  if (t == 255) bsum[blockIdx.x] = s[255];
}

__global__ __launch_bounds__(256) void k_scan2(const int* __restrict__ bsum, int NB, int* boff) {
  __shared__ int s[256];
  int t = threadIdx.x;
  int v = (t < NB) ? bsum[t] : 0;
  s[t] = v;
  __syncthreads();
  for (int d = 1; d < 256; d <<= 1) {
    int add = (t >= d) ? s[t - d] : 0;
    __syncthreads();
    s[t] += add;
    __syncthreads();
  }
  boff[t] = s[t] - v;
}

__global__ __launch_bounds__(256) void k_scan3(int* rowptr, const int* __restrict__ boff,
                                               int* cursor, int N, int E) {
  int i = blockIdx.x * 256 + threadIdx.x;
  if (i < N) {
    int v = rowptr[i] + boff[blockIdx.x];
    rowptr[i] = v;
    cursor[i] = v;
  }
  if (i == 0) rowptr[N] = E;
}

__global__ __launch_bounds__(256) void k_fill(const int* __restrict__ src,
                                              const int* __restrict__ dst, int E,
                                              int* cursor, int* __restrict__ csr) {
  int i0 = (blockIdx.x * 256 + threadIdx.x) * 4;
  if (i0 + 4 <= E) {
    int d0 = dst[i0], d1 = dst[i0+1], d2 = dst[i0+2], d3 = dst[i0+3];
    int s0 = src[i0], s1 = src[i0+1], s2 = src[i0+2], s3 = src[i0+3];
    int p0 = atomicAdd(&cursor[d0], 1);
    int p1 = atomicAdd(&cursor[d1], 1);
    int p2 = atomicAdd(&cursor[d2], 1);
    int p3 = atomicAdd(&cursor[d3], 1);
    csr[p0] = s0;
    csr[p1] = s1;
    csr[p2] = s2;
    csr[p3] = s3;
  } else {
    for (int i = i0; i < E; ++i) {
      int p = atomicAdd(&cursor[dst[i]], 1);
      csr[p] = src[i];
    }
  }
}

// ---------------------------------------------------------------------------
// Per-graph MLP head + log_softmax
// ---------------------------------------------------------------------------
__global__ __launch_bounds__(128) void k_mlp(const float* __restrict__ pool,
                                             const float* __restrict__ fc1W, const float* __restrict__ fc1b,
                                             const float* __restrict__ fc2W, const float* __restrict__ fc2b,
                                             const float* __restrict__ fc3W, const float* __restrict__ fc3b,
                                             float* __restrict__ out) {
  __shared__ float p[64], o1[128], o2[64], lg[10], red[2];
  int g = blockIdx.x, t = threadIdx.x;
  if (t < 64) p[t] = pool[(size_t)g * 64 + t];
  __syncthreads();
  {
    float a = fc1b[t];
    for (int k = 0; k < 64; ++k) a = fmaf(p[k], fc1W[k * 128 + t], a);
    o1[t] = fmaxf(a, 0.f);
  }
  __syncthreads();
  if (t < 64) {
    float a = fc2b[t];
    for (int k = 0; k < 128; ++k) a = fmaf(o1[k], fc2W[k * 64 + t], a);
    o2[t] = fmaxf(a, 0.f);
  }
  __syncthreads();
  if (t < 10) {
    float a = fc3b[t];
    for (int k = 0; k < 64; ++k) a = fmaf(o2[k], fc3W[k * 10 + t], a);
    lg[t] = a;
  }
  __syncthreads();
  if (t == 0) {
    float mx = lg[0];
    for (int j = 1; j < 10; ++j) mx = fmaxf(mx, lg[j]);
    float s = 0.f;
    for (int j = 0; j < 10; ++j) s += expf(lg[j] - mx);
    red[0] = mx;
    red[1] = logf(s);
  }
  __syncthreads();
  if (t < 10) out[(size_t)g * 10 + t] = lg[t] - red[0] - red[1];
}

// ---------------------------------------------------------------------------
extern "C" void kernel_launch(void* const* d_in, const int* in_sizes, int n_in,
                              void* d_out, int out_size, void* d_ws, size_t ws_size,
                              hipStream_t stream) {
  const float* x_in  = (const float*)d_in[0];
  const int*   ei    = (const int*)d_in[1];
  const int*   batch = (const int*)d_in[2];
  const float* W0    = (const float*)d_in[3];
  const float* b0    = (const float*)d_in[4];
  const float* cW1   = (const float*)d_in[5];
  const float* cb1   = (const float*)d_in[6];
  const float* gamma = (const float*)d_in[7];
  const float* beta  = (const float*)d_in[8];
  const float* cW2   = (const float*)d_in[9];
  const float* cb2   = (const float*)d_in[10];
  const float* fc1W  = (const float*)d_in[11];
  const float* fc1b  = (const float*)d_in[12];
  const float* fc2W  = (const float*)d_in[13];
  const float* fc2b  = (const float*)d_in[14];
  const float* fc3W  = (const float*)d_in[15];
  const float* fc3b  = (const float*)d_in[16];
  float* out = (float*)d_out;

  const int N = in_sizes[0] / 128;
  const int E = in_sizes[1] / 2;
  const int L = in_sizes[5] / (64 * 64);
  const int G = out_size / 10;
  const int* src = ei;
  const int* dst = ei + E;

  char* ws = (char*)d_ws;
  size_t off = 0;
  auto alloc = [&](size_t bytes) -> char* {
    char* p = ws + off;
    off += (bytes + 255) & ~(size_t)255;
    return p;
  };
  float* X    = (float*)alloc((size_t)N * 64 * 4);
  float* Bf   = (float*)alloc((size_t)N * 64 * 4);
  float* zb0  = (float*)alloc((size_t)N * 64 * 4);
  float* zb1  = (float*)alloc((size_t)N * 64 * 4);
  float* zb2  = (float*)alloc((size_t)N * 64 * 4);
  // ---- zeroed region: deg, pool, gstatAll (contiguous) ----
  int*   deg  = (int*)alloc((size_t)N * 4);
  float* pool = (float*)alloc((size_t)G * 64 * 4);
  float* gstatAll = (float*)alloc((size_t)3 * 128 * 4);
  char*  zero_end = ws + off;
  // ---------------------------------------------------------
  int*   rowptr = (int*)alloc((size_t)(N + 1) * 4);
  int*   cursor = (int*)alloc((size_t)N * 4);
  int*   csr    = (int*)alloc((size_t)E * 4);
  int*   bsum   = (int*)alloc(256 * 4);
  int*   boff   = (int*)alloc(256 * 4);
  float* zbuf[3] = {zb0, zb1, zb2};

  hipMemsetAsync(deg, 0, (size_t)(zero_end - (char*)deg), stream);

  const int tileGrid  = (N + 15) / 16;
  const int edge4Grid = (E / 4 + 255) / 256 + 1;

  // X = relu(x @ W0 + b0); Z1 = SCALING*project(X)
  k_mm0<<<tileGrid, 256, 0, stream>>>(x_in, W0, b0, X, zbuf[0], N, 128);

  // CSR build
  k_deg<<<edge4Grid, 256, 0, stream>>>(dst, E, deg);
  const int NB = (N + 255) / 256;
  k_scan1<<<NB, 256, 0, stream>>>(deg, N, rowptr, bsum);
  k_scan2<<<1, 256, 0, stream>>>(bsum, NB, boff);
  k_scan3<<<NB, 256, 0, stream>>>(rowptr, boff, cursor, N, E);
  k_fill<<<edge4Grid, 256, 0, stream>>>(src, dst, E, cursor, csr);

  for (int i = 0; i < L; ++i) {
    float* gstat = gstatAll + (size_t)i * 128;
    const int last = (i == L - 1);
    k_layer1<<<tileGrid, 256, 0, stream>>>(X, rowptr, csr,
                                           cW1 + (size_t)i * 64 * 64, cb1 + i * 64,
                                           Bf, gstat, N);
    k_layer2<<<tileGrid, 256, 0, stream>>>(Bf, cW2 + (size_t)i * 64 * 64, cb2 + i * 64,
                                           gstat, gamma + i * 64, beta + i * 64,
                                           last ? nullptr : X,
                                           zbuf[i],
                                           (i == 0) ? nullptr : zbuf[i - 1],
                                           last ? nullptr : zbuf[i + 1],
                                           batch, pool, N);
  }

  k_mlp<<<G, 128, 0, stream>>>(pool, fc1W, fc1b, fc2W, fc2b, fc3W, fc3b, out);
}

// Round 7
// 538.587 us; speedup vs baseline: 1.1686x; 1.1686x over previous
//
#include <hip/hip_runtime.h>
#include <math.h>

#define SCALING_F 0.46211715726000974f   // tanh(0.5)
#define MAXNORM_F 0.996f                 // 1 - BALL_EPS
#define MINNORM_F 1e-15f
#define BN_EPS_F  1e-5f

// reduce over the 16-lane group holding one row
__device__ __forceinline__ float rsum16(float v) {
  v += __shfl_xor(v, 1, 64);
  v += __shfl_xor(v, 2, 64);
  v += __shfl_xor(v, 4, 64);
  v += __shfl_xor(v, 8, 64);
  return v;
}

// six independent 16-lane reductions, pipelined
__device__ __forceinline__ void rsum16x6(float& a, float& b, float& c,
                                         float& d, float& e, float& f) {
#pragma unroll
  for (int o = 1; o <= 8; o <<= 1) {
    a += __shfl_xor(a, o, 64);
    b += __shfl_xor(b, o, 64);
    c += __shfl_xor(c, o, 64);
    d += __shfl_xor(d, o, 64);
    e += __shfl_xor(e, o, 64);
    f += __shfl_xor(f, o, 64);
  }
}

// ---------------------------------------------------------------------------
// mm0 (64-row tile): X = relu(x_in @ W0 + b0)  (K=128), fused proj epilogue:
//      Z[row] = SCALING * project(X[row])
// ---------------------------------------------------------------------------
__global__ __launch_bounds__(256) void k_mm0(
    const float* __restrict__ A, const float* __restrict__ B,
    const float* __restrict__ bias, float* __restrict__ X,
    float* __restrict__ Z, int M, int K)
{
  __shared__ float As[64][65];
  __shared__ float Bs[64][64];
  const int tid  = threadIdx.x;
  const int c0   = (tid & 15) * 4;
  const int r0   = (tid >> 4) * 4;
  const int rblk = blockIdx.x * 64;
  float acc[4][4] = {{0.f,0.f,0.f,0.f},{0.f,0.f,0.f,0.f},
                     {0.f,0.f,0.f,0.f},{0.f,0.f,0.f,0.f}};

  for (int kk = 0; kk < K; kk += 64) {
#pragma unroll
    for (int j = 0; j < 4; ++j) {
      int f = j * 256 + tid;
      int bk = f >> 4, bc = (f & 15) * 4;
      *(float4*)&Bs[bk][bc] = *(const float4*)&B[(size_t)(kk + bk) * 64 + bc];
    }
#pragma unroll
    for (int j = 0; j < 4; ++j) {
      int f = j * 256 + tid;
      int ar = f >> 4, ac = (f & 15) * 4;
      int row = rblk + ar;
      float4 av = make_float4(0.f, 0.f, 0.f, 0.f);
      if (row < M) av = *(const float4*)&A[(size_t)row * K + kk + ac];
      As[ar][ac + 0] = av.x;
      As[ar][ac + 1] = av.y;
      As[ar][ac + 2] = av.z;
      As[ar][ac + 3] = av.w;
    }
    __syncthreads();
#pragma unroll 16
    for (int k = 0; k < 64; ++k) {
      float4 b4 = *(float4*)&Bs[k][c0];
      float a0 = As[r0 + 0][k], a1 = As[r0 + 1][k];
      float a2 = As[r0 + 2][k], a3 = As[r0 + 3][k];
      acc[0][0] = fmaf(a0,b4.x,acc[0][0]); acc[0][1] = fmaf(a0,b4.y,acc[0][1]);
      acc[0][2] = fmaf(a0,b4.z,acc[0][2]); acc[0][3] = fmaf(a0,b4.w,acc[0][3]);
      acc[1][0] = fmaf(a1,b4.x,acc[1][0]); acc[1][1] = fmaf(a1,b4.y,acc[1][1]);
      acc[1][2] = fmaf(a1,b4.z,acc[1][2]); acc[1][3] = fmaf(a1,b4.w,acc[1][3]);
      acc[2][0] = fmaf(a2,b4.x,acc[2][0]); acc[2][1] = fmaf(a2,b4.y,acc[2][1]);
      acc[2][2] = fmaf(a2,b4.z,acc[2][2]); acc[2][3] = fmaf(a2,b4.w,acc[2][3]);
      acc[3][0] = fmaf(a3,b4.x,acc[3][0]); acc[3][1] = fmaf(a3,b4.y,acc[3][1]);
      acc[3][2] = fmaf(a3,b4.z,acc[3][2]); acc[3][3] = fmaf(a3,b4.w,acc[3][3]);
    }
    __syncthreads();
  }

  float b0 = bias[c0+0], b1 = bias[c0+1], b2 = bias[c0+2], b3 = bias[c0+3];
#pragma unroll
  for (int j = 0; j < 4; ++j) {
    int row = rblk + r0 + j;
    float v0 = fmaxf(acc[j][0] + b0, 0.f);
    float v1 = fmaxf(acc[j][1] + b1, 0.f);
    float v2 = fmaxf(acc[j][2] + b2, 0.f);
    float v3 = fmaxf(acc[j][3] + b3, 0.f);
    if (row < M)
      *(float4*)&X[(size_t)row * 64 + c0] = make_float4(v0, v1, v2, v3);
    float sx = rsum16(v0*v0 + v1*v1 + v2*v2 + v3*v3);
    float norm = fmaxf(sqrtf(sx), MINNORM_F);
    float s = ((norm > MAXNORM_F) ? (MAXNORM_F / norm) : 1.0f) * SCALING_F;
    if (row < M)
      *(float4*)&Z[(size_t)row * 64 + c0] = make_float4(v0*s, v1*s, v2*s, v3*s);
  }
}

// ---------------------------------------------------------------------------
// K1 (64-row tile): h = relu((x[r] + sum_nb x[nb]) @ W1 + b1), fused BN stats.
// ---------------------------------------------------------------------------
__global__ __launch_bounds__(256) void k_layer1(
    const float* __restrict__ x, const int* __restrict__ rowptr,
    const int* __restrict__ csr, const float* __restrict__ B,
    const float* __restrict__ bias, float* __restrict__ h,
    float* __restrict__ gstat, int M)
{
  __shared__ float As[64][65];
  __shared__ float Bs[64][64];
  const int tid  = threadIdx.x;
  const int c0   = (tid & 15) * 4;
  const int r0   = (tid >> 4) * 4;
  const int rblk = blockIdx.x * 64;
  const int wv   = tid >> 6;
  const int lane = tid & 63;

#pragma unroll
  for (int j = 0; j < 4; ++j) {
    int f = j * 256 + tid;
    int bk = f >> 4, bc = (f & 15) * 4;
    *(float4*)&Bs[bk][bc] = *(const float4*)&B[(size_t)bk * 64 + bc];
  }
  for (int rr = 0; rr < 16; ++rr) {
    int lr = wv * 16 + rr;
    int r  = rblk + lr;
    float acc = 0.f;
    if (r < M) {
      acc = x[(size_t)r * 64 + lane];
      int beg = rowptr[r], end = rowptr[r + 1];
      int j = beg;
      for (; j + 8 <= end; j += 8) {
        int n0 = csr[j+0], n1 = csr[j+1], n2 = csr[j+2], n3 = csr[j+3];
        int n4 = csr[j+4], n5 = csr[j+5], n6 = csr[j+6], n7 = csr[j+7];
        float v0 = x[(size_t)n0*64+lane], v1 = x[(size_t)n1*64+lane];
        float v2 = x[(size_t)n2*64+lane], v3 = x[(size_t)n3*64+lane];
        float v4 = x[(size_t)n4*64+lane], v5 = x[(size_t)n5*64+lane];
        float v6 = x[(size_t)n6*64+lane], v7 = x[(size_t)n7*64+lane];
        acc += ((v0+v1)+(v2+v3)) + ((v4+v5)+(v6+v7));
      }
      if (j + 4 <= end) {
        int n0 = csr[j+0], n1 = csr[j+1], n2 = csr[j+2], n3 = csr[j+3];
        float v0 = x[(size_t)n0*64+lane], v1 = x[(size_t)n1*64+lane];
        float v2 = x[(size_t)n2*64+lane], v3 = x[(size_t)n3*64+lane];
        acc += (v0+v1)+(v2+v3);
        j += 4;
      }
      for (; j < end; ++j) acc += x[(size_t)csr[j]*64+lane];
    }
    As[lr][lane] = acc;
  }
  __syncthreads();

  float acc[4][4] = {{0.f,0.f,0.f,0.f},{0.f,0.f,0.f,0.f},
                     {0.f,0.f,0.f,0.f},{0.f,0.f,0.f,0.f}};
#pragma unroll 16
  for (int k = 0; k < 64; ++k) {
    float4 b4 = *(float4*)&Bs[k][c0];
    float a0 = As[r0 + 0][k], a1 = As[r0 + 1][k];
    float a2 = As[r0 + 2][k], a3 = As[r0 + 3][k];
    acc[0][0] = fmaf(a0,b4.x,acc[0][0]); acc[0][1] = fmaf(a0,b4.y,acc[0][1]);
    acc[0][2] = fmaf(a0,b4.z,acc[0][2]); acc[0][3] = fmaf(a0,b4.w,acc[0][3]);
    acc[1][0] = fmaf(a1,b4.x,acc[1][0]); acc[1][1] = fmaf(a1,b4.y,acc[1][1]);
    acc[1][2] = fmaf(a1,b4.z,acc[1][2]); acc[1][3] = fmaf(a1,b4.w,acc[1][3]);
    acc[2][0] = fmaf(a2,b4.x,acc[2][0]); acc[2][1] = fmaf(a2,b4.y,acc[2][1]);
    acc[2][2] = fmaf(a2,b4.z,acc[2][2]); acc[2][3] = fmaf(a2,b4.w,acc[2][3]);
    acc[3][0] = fmaf(a3,b4.x,acc[3][0]); acc[3][1] = fmaf(a3,b4.y,acc[3][1]);
    acc[3][2] = fmaf(a3,b4.z,acc[3][2]); acc[3][3] = fmaf(a3,b4.w,acc[3][3]);
  }
  __syncthreads();   // Bs dead after this; reused as stats scratch

  float b0 = bias[c0+0], b1 = bias[c0+1], b2 = bias[c0+2], b3 = bias[c0+3];
  float s[4] = {0.f,0.f,0.f,0.f}, q[4] = {0.f,0.f,0.f,0.f};
#pragma unroll
  for (int j = 0; j < 4; ++j) {
    int row = rblk + r0 + j;
    if (row >= M) continue;
    float4 v;
    v.x = fmaxf(acc[j][0] + b0, 0.f);
    v.y = fmaxf(acc[j][1] + b1, 0.f);
    v.z = fmaxf(acc[j][2] + b2, 0.f);
    v.w = fmaxf(acc[j][3] + b3, 0.f);
    s[0] += v.x; s[1] += v.y; s[2] += v.z; s[3] += v.w;
    q[0] += v.x*v.x; q[1] += v.y*v.y; q[2] += v.z*v.z; q[3] += v.w*v.w;
    *(float4*)&h[(size_t)row * 64 + c0] = v;
  }
  {
    float* st = (float*)Bs;           // [0:1024) sums, [1024:2048) sumsq
    int g = tid >> 4;
#pragma unroll
    for (int i = 0; i < 4; ++i) {
      st[g * 64 + c0 + i]        = s[i];
      st[1024 + g * 64 + c0 + i] = q[i];
    }
    __syncthreads();
    if (tid < 64) {
      float a = 0.f, b = 0.f;
#pragma unroll
      for (int g2 = 0; g2 < 16; ++g2) {
        a += st[g2 * 64 + tid];
        b += st[1024 + g2 * 64 + tid];
      }
      atomicAdd(&gstat[tid], a);
      atomicAdd(&gstat[64 + tid], b);
    }
  }
}

// ---------------------------------------------------------------------------
// K2 (16-row tile): xn = relu(BN(h) @ W2 + b2), col63 = 0; fused hyp epilogue.
// BN scale/shift computed in-block from gstat.
// If Zn != null: write X and Zn. Else (last layer): logmap0 + pool.
// ---------------------------------------------------------------------------
__global__ __launch_bounds__(256) void k_layer2(
    const float* __restrict__ A, const float* __restrict__ B,
    const float* __restrict__ bias,
    const float* __restrict__ gstat, const float* __restrict__ gamma,
    const float* __restrict__ beta,
    float* __restrict__ X,
    const float* __restrict__ Zc, const float* Zp, float* Zn,
    const int* __restrict__ batch, float* __restrict__ pool, int M)
{
  __shared__ float As[16][65];
  __shared__ float Bs[64][64];
  __shared__ float scl_s[64], shf_s[64];
  const int tid   = threadIdx.x;
  const int c0    = (tid & 15) * 4;
  const int row_l = tid >> 4;
  const int rblk  = blockIdx.x * 16;
  const int row   = rblk + row_l;
  const bool valid = (row < M);

  if (tid < 64) {
    float mu  = gstat[tid] / (float)M;
    float var = gstat[64 + tid] / (float)M - mu * mu;
    float sv  = gamma[tid] / sqrtf(var + BN_EPS_F);
    scl_s[tid] = sv;
    shf_s[tid] = beta[tid] - mu * sv;
  }
  __syncthreads();

#pragma unroll
  for (int j = 0; j < 4; ++j) {
    int f = j * 256 + tid;
    int bk = f >> 4, bc = (f & 15) * 4;
    *(float4*)&Bs[bk][bc] = *(const float4*)&B[(size_t)bk * 64 + bc];
  }
  {
    int ar = tid >> 4, ac = (tid & 15) * 4;
    int r = rblk + ar;
    float4 av = make_float4(0.f, 0.f, 0.f, 0.f);
    if (r < M) av = *(const float4*)&A[(size_t)r * 64 + ac];
    As[ar][ac + 0] = fmaf(av.x, scl_s[ac+0], shf_s[ac+0]);
    As[ar][ac + 1] = fmaf(av.y, scl_s[ac+1], shf_s[ac+1]);
    As[ar][ac + 2] = fmaf(av.z, scl_s[ac+2], shf_s[ac+2]);
    As[ar][ac + 3] = fmaf(av.w, scl_s[ac+3], shf_s[ac+3]);
  }

  // prefetch zc/zp so they're in flight during staging barrier + FMA loop
  float4 zc4 = make_float4(0.f, 0.f, 0.f, 0.f);
  float4 zp4 = make_float4(0.f, 0.f, 0.f, 0.f);
  if (valid) zc4 = *(const float4*)&Zc[(size_t)row * 64 + c0];
  if (valid && Zp != nullptr) zp4 = *(const float4*)&Zp[(size_t)row * 64 + c0];
  __syncthreads();

  float acc[4] = {0.f, 0.f, 0.f, 0.f};
#pragma unroll 16
  for (int k = 0; k < 64; ++k) {
    float4 b4 = *(float4*)&Bs[k][c0];
    float a = As[row_l][k];
    acc[0] = fmaf(a, b4.x, acc[0]);
    acc[1] = fmaf(a, b4.y, acc[1]);
    acc[2] = fmaf(a, b4.z, acc[2]);
    acc[3] = fmaf(a, b4.w, acc[3]);
  }

  float xv[4];
  xv[0] = fmaxf(acc[0] + bias[c0+0], 0.f);
  xv[1] = fmaxf(acc[1] + bias[c0+1], 0.f);
  xv[2] = fmaxf(acc[2] + bias[c0+2], 0.f);
  xv[3] = fmaxf(acc[3] + bias[c0+3], 0.f);
  if (c0 == 60) xv[3] = 0.f;     // x[:, -1] = 0
  if (valid && X != nullptr)
    *(float4*)&X[(size_t)row * 64 + c0] = make_float4(xv[0],xv[1],xv[2],xv[3]);

  float zcv[4] = {zc4.x, zc4.y, zc4.z, zc4.w};
  float zpv[4] = {zp4.x, zp4.y, zp4.z, zp4.w};

  // six independent dot-product partials
  float p1 = xv[0]*xv[0] + xv[1]*xv[1] + xv[2]*xv[2] + xv[3]*xv[3];   // Σxv²
  float p2 = zcv[0]*zcv[0]+zcv[1]*zcv[1]+zcv[2]*zcv[2]+zcv[3]*zcv[3]; // Σzc²
  float p3 = zpv[0]*zpv[0]+zpv[1]*zpv[1]+zpv[2]*zpv[2]+zpv[3]*zpv[3]; // Σzp²
  float p4 = zpv[0]*zcv[0]+zpv[1]*zcv[1]+zpv[2]*zcv[2]+zpv[3]*zcv[3]; // Σzp·zc
  float p5 = zpv[0]*xv[0]+zpv[1]*xv[1]+zpv[2]*xv[2]+zpv[3]*xv[3];     // Σzp·xv
  float p6 = zcv[0]*xv[0]+zcv[1]*xv[1]+zcv[2]*xv[2]+zcv[3]*xv[3];     // Σzc·xv
  rsum16x6(p1, p2, p3, p4, p5, p6);
  float zc63 = __shfl(zcv[3], 15, 16);   // element 63 of this row
  float zp63 = __shfl(zpv[3], 15, 16);

  // ---- scalar chain (uniform within the 16-lane group) ----
  float nzc2 = fmaxf(p2, MINNORM_F);
  float icz  = 1.0f / nzc2;
  float na2  = p2 * icz * icz;           // Σa²
  float r2   = na2 - 1.0f;
  float a63  = zc63 * icz;

  float sxn = fmaxf(sqrtf(p1), MINNORM_F);
  float sc  = ((sxn > MAXNORM_F) ? (MAXNORM_F / sxn) : 1.0f) * SCALING_F;
  float Sch2   = sc * sc * p1;           // Σch²   (ch63 = 0)
  float Szp_a  = p4 * icz;               // Σzp·a
  float Sa_ch  = sc * p6 * icz;          // Σa·ch
  float Szp_ch = sc * p5;                // Σzp·ch
  float Su_a   = Szp_a - na2;            // Σ(zp−a)·a
  float Su2    = p3 - 2.0f * Szp_a + na2;
  float nu2    = fmaxf(Su2, MINNORM_F);
  float t1     = r2 / nu2;
  float Szp22  = fmaxf(t1*t1*Su2 + 2.0f*t1*Su_a + na2, 0.0f);  // Σzp2²
  float npn    = fmaxf(sqrtf(Szp22), MINNORM_F);
  float ipn    = 1.0f / npn;
  float zp2_63 = t1 * (zp63 - a63) + a63;
  float Szp2ch = t1 * (Szp_ch - Sa_ch) + Sa_ch;
  float rdc    = -ipn * Szp2ch;          // Σr·ch  (q·ch = ch63 = 0)
  float rdr    = 1.0f - 2.0f*ipn*zp2_63 + ipn*ipn*Szp22;       // Σr·r
  float m2     = 2.0f * rdc / rdr;
  float Szp2a  = t1 * Su_a + na2;        // Σzp2·a
  float Srr_a  = a63 - ipn * Szp2a;      // Σr·a
  float Sc2a   = Sa_ch - m2 * Srr_a;     // Σc2·a
  float Sc22   = Sch2 - 2.0f*m2*rdc + m2*m2*rdr;               // Σc2²
  float Sc2ma  = Sc22 - 2.0f*Sc2a + na2; // Σ(c2−a)²
  float nu22   = fmaxf(Sc2ma, MINNORM_F);
  float t2     = r2 / nu22;

  // ---- per-lane vector tail ----
  float zn[4];
#pragma unroll
  for (int i = 0; i < 4; ++i) {
    float ai  = zcv[i] * icz;
    float zp2 = t1 * (zpv[i] - ai) + ai;
    float rri = (((c0 + i) == 63) ? 1.0f : 0.0f) - ipn * zp2;
    float c2  = sc * xv[i] - m2 * rri;
    zn[i]     = t2 * (c2 - ai) + ai;
  }

  if (Zn != nullptr) {
    if (valid)
      *(float4*)&Zn[(size_t)row * 64 + c0] = make_float4(zn[0],zn[1],zn[2],zn[3]);
  } else {
    float Szn2 = fmaxf(t2*t2*Sc2ma + 2.0f*t2*(Sc2a - na2) + na2, 0.0f);
    float yn  = fmaxf(sqrtf(Szn2), MINNORM_F);
    float t   = fminf(yn, 1.0f);
    float ath = 0.5f * logf((1.0f + t) / (1.0f - t));
    float wsc = ath / yn;
    if (valid) {
      int b = batch[row];
      float* p = &pool[(size_t)b * 64 + c0];
      atomicAdd(p + 0, zn[0] * wsc);
      atomicAdd(p + 1, zn[1] * wsc);
      atomicAdd(p + 2, zn[2] * wsc);
      atomicAdd(p + 3, zn[3] * wsc);
    }
  }
}

// ---------------------------------------------------------------------------
// CSR build
// ---------------------------------------------------------------------------
__global__ __launch_bounds__(256) void k_deg(const int* __restrict__ dst, int E, int* deg) {
  int i0 = (blockIdx.x * 256 + threadIdx.x) * 4;
  if (i0 + 4 <= E) {
    int d0 = dst[i0], d1 = dst[i0+1], d2 = dst[i0+2], d3 = dst[i0+3];
    atomicAdd(&deg[d0], 1);
    atomicAdd(&deg[d1], 1);
    atomicAdd(&deg[d2], 1);
    atomicAdd(&deg[d3], 1);
  } else {
    for (int i = i0; i < E; ++i) atomicAdd(&deg[dst[i]], 1);
  }
}

__global__ __launch_bounds__(256) void k_scan1(const int* __restrict__ deg, int N,
                                               int* rowptr, int* bsum) {
  __shared__ int s[256];
  int t = threadIdx.x;
  int i = blockIdx.x * 256 + t;
  int v = (i < N) ? deg[i] : 0;
  s[t] = v;
  __syncthreads();
  for (int d = 1; d < 256; d <<= 1) {
    int add = (t >= d) ? s[t - d] : 0;
    __syncthreads();
    s[t] += add;
    __syncthreads();
  }
  if (i < N) rowptr[i] = s[t] - v;
  if (t == 255) bsum[blockIdx.x] = s[255];
}

__global__ __launch_bounds__(256) void k_scan2(const int* __restrict__ bsum, int NB, int* boff) {
  __shared__ int s[256];
  int t = threadIdx.x;
  int v = (t < NB) ? bsum[t] : 0;
  s[t] = v;
  __syncthreads();
  for (int d = 1; d < 256; d <<= 1) {
    int add = (t >= d) ? s[t - d] : 0;
    __syncthreads();
    s[t] += add;
    __syncthreads();
  }
  boff[t] = s[t] - v;
}

__global__ __launch_bounds__(256) void k_scan3(int* rowptr, const int* __restrict__ boff,
                                               int* cursor, int N, int E) {
  int i = blockIdx.x * 256 + threadIdx.x;
  if (i < N) {
    int v = rowptr[i] + boff[blockIdx.x];
    rowptr[i] = v;
    cursor[i] = v;
  }
  if (i == 0) rowptr[N] = E;
}

__global__ __launch_bounds__(256) void k_fill(const int* __restrict__ src,
                                              const int* __restrict__ dst, int E,
                                              int* cursor, int* __restrict__ csr) {
  int i0 = (blockIdx.x * 256 + threadIdx.x) * 4;
  if (i0 + 4 <= E) {
    int d0 = dst[i0], d1 = dst[i0+1], d2 = dst[i0+2], d3 = dst[i0+3];
    int s0 = src[i0], s1 = src[i0+1], s2 = src[i0+2], s3 = src[i0+3];
    int p0 = atomicAdd(&cursor[d0], 1);
    int p1 = atomicAdd(&cursor[d1], 1);
    int p2 = atomicAdd(&cursor[d2], 1);
    int p3 = atomicAdd(&cursor[d3], 1);
    csr[p0] = s0;
    csr[p1] = s1;
    csr[p2] = s2;
    csr[p3] = s3;
  } else {
    for (int i = i0; i < E; ++i) {
      int p = atomicAdd(&cursor[dst[i]], 1);
      csr[p] = src[i];
    }
  }
}

// ---------------------------------------------------------------------------
// Per-graph MLP head + log_softmax
// ---------------------------------------------------------------------------
__global__ __launch_bounds__(128) void k_mlp(const float* __restrict__ pool,
                                             const float* __restrict__ fc1W, const float* __restrict__ fc1b,
                                             const float* __restrict__ fc2W, const float* __restrict__ fc2b,
                                             const float* __restrict__ fc3W, const float* __restrict__ fc3b,
                                             float* __restrict__ out) {
  __shared__ float p[64], o1[128], o2[64], lg[10], red[2];
  int g = blockIdx.x, t = threadIdx.x;
  if (t < 64) p[t] = pool[(size_t)g * 64 + t];
  __syncthreads();
  {
    float a = fc1b[t];
    for (int k = 0; k < 64; ++k) a = fmaf(p[k], fc1W[k * 128 + t], a);
    o1[t] = fmaxf(a, 0.f);
  }
  __syncthreads();
  if (t < 64) {
    float a = fc2b[t];
    for (int k = 0; k < 128; ++k) a = fmaf(o1[k], fc2W[k * 64 + t], a);
    o2[t] = fmaxf(a, 0.f);
  }
  __syncthreads();
  if (t < 10) {
    float a = fc3b[t];
    for (int k = 0; k < 64; ++k) a = fmaf(o2[k], fc3W[k * 10 + t], a);
    lg[t] = a;
  }
  __syncthreads();
  if (t == 0) {
    float mx = lg[0];
    for (int j = 1; j < 10; ++j) mx = fmaxf(mx, lg[j]);
    float s = 0.f;
    for (int j = 0; j < 10; ++j) s += expf(lg[j] - mx);
    red[0] = mx;
    red[1] = logf(s);
  }
  __syncthreads();
  if (t < 10) out[(size_t)g * 10 + t] = lg[t] - red[0] - red[1];
}

// ---------------------------------------------------------------------------
extern "C" void kernel_launch(void* const* d_in, const int* in_sizes, int n_in,
                              void* d_out, int out_size, void* d_ws, size_t ws_size,
                              hipStream_t stream) {
  const float* x_in  = (const float*)d_in[0];
  const int*   ei    = (const int*)d_in[1];
  const int*   batch = (const int*)d_in[2];
  const float* W0    = (const float*)d_in[3];
  const float* b0    = (const float*)d_in[4];
  const float* cW1   = (const float*)d_in[5];
  const float* cb1   = (const float*)d_in[6];
  const float* gamma = (const float*)d_in[7];
  const float* beta  = (const float*)d_in[8];
  const float* cW2   = (const float*)d_in[9];
  const float* cb2   = (const float*)d_in[10];
  const float* fc1W  = (const float*)d_in[11];
  const float* fc1b  = (const float*)d_in[12];
  const float* fc2W  = (const float*)d_in[13];
  const float* fc2b  = (const float*)d_in[14];
  const float* fc3W  = (const float*)d_in[15];
  const float* fc3b  = (const float*)d_in[16];
  float* out = (float*)d_out;

  const int N = in_sizes[0] / 128;
  const int E = in_sizes[1] / 2;
  const int L = in_sizes[5] / (64 * 64);
  const int G = out_size / 10;
  const int* src = ei;
  const int* dst = ei + E;

  char* ws = (char*)d_ws;
  size_t off = 0;
  auto alloc = [&](size_t bytes) -> char* {
    char* p = ws + off;
    off += (bytes + 255) & ~(size_t)255;
    return p;
  };
  float* X    = (float*)alloc((size_t)N * 64 * 4);
  float* Bf   = (float*)alloc((size_t)N * 64 * 4);
  float* zb0  = (float*)alloc((size_t)N * 64 * 4);
  float* zb1  = (float*)alloc((size_t)N * 64 * 4);
  float* zb2  = (float*)alloc((size_t)N * 64 * 4);
  // ---- zeroed region: deg, pool, gstatAll (contiguous) ----
  int*   deg  = (int*)alloc((size_t)N * 4);
  float* pool = (float*)alloc((size_t)G * 64 * 4);
  float* gstatAll = (float*)alloc((size_t)3 * 128 * 4);
  char*  zero_end = ws + off;
  // ---------------------------------------------------------
  int*   rowptr = (int*)alloc((size_t)(N + 1) * 4);
  int*   cursor = (int*)alloc((size_t)N * 4);
  int*   csr    = (int*)alloc((size_t)E * 4);
  int*   bsum   = (int*)alloc(256 * 4);
  int*   boff   = (int*)alloc(256 * 4);
  float* zbuf[3] = {zb0, zb1, zb2};

  hipMemsetAsync(deg, 0, (size_t)(zero_end - (char*)deg), stream);

  const int mmGrid    = (N + 63) / 64;    // 64-row tiles (mm0, layer1)
  const int tileGrid  = (N + 15) / 16;    // 16-row tiles (layer2)
  const int edge4Grid = (E / 4 + 255) / 256 + 1;

  // X = relu(x @ W0 + b0); Z1 = SCALING*project(X)
  k_mm0<<<mmGrid, 256, 0, stream>>>(x_in, W0, b0, X, zbuf[0], N, 128);

  // CSR build
  k_deg<<<edge4Grid, 256, 0, stream>>>(dst, E, deg);
  const int NB = (N + 255) / 256;
  k_scan1<<<NB, 256, 0, stream>>>(deg, N, rowptr, bsum);
  k_scan2<<<1, 256, 0, stream>>>(bsum, NB, boff);
  k_scan3<<<NB, 256, 0, stream>>>(rowptr, boff, cursor, N, E);
  k_fill<<<edge4Grid, 256, 0, stream>>>(src, dst, E, cursor, csr);

  for (int i = 0; i < L; ++i) {
    float* gstat = gstatAll + (size_t)i * 128;
    const int last = (i == L - 1);
    k_layer1<<<mmGrid, 256, 0, stream>>>(X, rowptr, csr,
                                         cW1 + (size_t)i * 64 * 64, cb1 + i * 64,
                                         Bf, gstat, N);
    k_layer2<<<tileGrid, 256, 0, stream>>>(Bf, cW2 + (size_t)i * 64 * 64, cb2 + i * 64,
                                           gstat, gamma + i * 64, beta + i * 64,
                                           last ? nullptr : X,
                                           zbuf[i],
                                           (i == 0) ? nullptr : zbuf[i - 1],
                                           last ? nullptr : zbuf[i + 1],
                                           batch, pool, N);
  }

  k_mlp<<<G, 128, 0, stream>>>(pool, fc1W, fc1b, fc2W, fc2b, fc3W, fc3b, out);
}

// Round 8
// 516.877 us; speedup vs baseline: 1.2177x; 1.0420x over previous
//
#include <hip/hip_runtime.h>
#include <hip/hip_fp16.h>
#include <math.h>

#define SCALING_F 0.46211715726000974f   // tanh(0.5)
#define MAXNORM_F 0.996f                 // 1 - BALL_EPS
#define MINNORM_F 1e-15f
#define BN_EPS_F  1e-5f

// reduce over the 16-lane group holding one row
__device__ __forceinline__ float rsum16(float v) {
  v += __shfl_xor(v, 1, 64);
  v += __shfl_xor(v, 2, 64);
  v += __shfl_xor(v, 4, 64);
  v += __shfl_xor(v, 8, 64);
  return v;
}

// six independent 16-lane reductions, pipelined
__device__ __forceinline__ void rsum16x6(float& a, float& b, float& c,
                                         float& d, float& e, float& f) {
#pragma unroll
  for (int o = 1; o <= 8; o <<= 1) {
    a += __shfl_xor(a, o, 64);
    b += __shfl_xor(b, o, 64);
    c += __shfl_xor(c, o, 64);
    d += __shfl_xor(d, o, 64);
    e += __shfl_xor(e, o, 64);
    f += __shfl_xor(f, o, 64);
  }
}

// packed fp16x4 load/store (8B)
__device__ __forceinline__ void store_h4(__half* p, float v0, float v1,
                                         float v2, float v3) {
  __half2 a = __halves2half2(__float2half(v0), __float2half(v1));
  __half2 b = __halves2half2(__float2half(v2), __float2half(v3));
  uint2 u;
  u.x = *(unsigned int*)&a;
  u.y = *(unsigned int*)&b;
  *(uint2*)p = u;
}
__device__ __forceinline__ void load_h4(const __half* p, float& v0, float& v1,
                                        float& v2, float& v3) {
  uint2 u = *(const uint2*)p;
  __half2 a = *(__half2*)&u.x;
  __half2 b = *(__half2*)&u.y;
  v0 = __low2float(a); v1 = __high2float(a);
  v2 = __low2float(b); v3 = __high2float(b);
}
__device__ __forceinline__ float h2f(float v) {   // fp16 round-trip
  return __half2float(__float2half(v));
}

// ---------------------------------------------------------------------------
// mm0 (64-row tile): X = relu(x_in @ W0 + b0)  (K=128), fp16 X, fused proj:
//      Z[row] = SCALING * project(X[row])   (Z fp32)
// ---------------------------------------------------------------------------
__global__ __launch_bounds__(256) void k_mm0(
    const float* __restrict__ A, const float* __restrict__ B,
    const float* __restrict__ bias, __half* __restrict__ X,
    float* __restrict__ Z, int M, int K)
{
  __shared__ float As[64][65];
  __shared__ float Bs[64][64];
  const int tid  = threadIdx.x;
  const int c0   = (tid & 15) * 4;
  const int r0   = (tid >> 4) * 4;
  const int rblk = blockIdx.x * 64;
  float acc[4][4] = {{0.f,0.f,0.f,0.f},{0.f,0.f,0.f,0.f},
                     {0.f,0.f,0.f,0.f},{0.f,0.f,0.f,0.f}};

  for (int kk = 0; kk < K; kk += 64) {
#pragma unroll
    for (int j = 0; j < 4; ++j) {
      int f = j * 256 + tid;
      int bk = f >> 4, bc = (f & 15) * 4;
      *(float4*)&Bs[bk][bc] = *(const float4*)&B[(size_t)(kk + bk) * 64 + bc];
    }
#pragma unroll
    for (int j = 0; j < 4; ++j) {
      int f = j * 256 + tid;
      int ar = f >> 4, ac = (f & 15) * 4;
      int row = rblk + ar;
      float4 av = make_float4(0.f, 0.f, 0.f, 0.f);
      if (row < M) av = *(const float4*)&A[(size_t)row * K + kk + ac];
      As[ar][ac + 0] = av.x;
      As[ar][ac + 1] = av.y;
      As[ar][ac + 2] = av.z;
      As[ar][ac + 3] = av.w;
    }
    __syncthreads();
#pragma unroll 16
    for (int k = 0; k < 64; ++k) {
      float4 b4 = *(float4*)&Bs[k][c0];
      float a0 = As[r0 + 0][k], a1 = As[r0 + 1][k];
      float a2 = As[r0 + 2][k], a3 = As[r0 + 3][k];
      acc[0][0] = fmaf(a0,b4.x,acc[0][0]); acc[0][1] = fmaf(a0,b4.y,acc[0][1]);
      acc[0][2] = fmaf(a0,b4.z,acc[0][2]); acc[0][3] = fmaf(a0,b4.w,acc[0][3]);
      acc[1][0] = fmaf(a1,b4.x,acc[1][0]); acc[1][1] = fmaf(a1,b4.y,acc[1][1]);
      acc[1][2] = fmaf(a1,b4.z,acc[1][2]); acc[1][3] = fmaf(a1,b4.w,acc[1][3]);
      acc[2][0] = fmaf(a2,b4.x,acc[2][0]); acc[2][1] = fmaf(a2,b4.y,acc[2][1]);
      acc[2][2] = fmaf(a2,b4.z,acc[2][2]); acc[2][3] = fmaf(a2,b4.w,acc[2][3]);
      acc[3][0] = fmaf(a3,b4.x,acc[3][0]); acc[3][1] = fmaf(a3,b4.y,acc[3][1]);
      acc[3][2] = fmaf(a3,b4.z,acc[3][2]); acc[3][3] = fmaf(a3,b4.w,acc[3][3]);
    }
    __syncthreads();
  }

  float b0 = bias[c0+0], b1 = bias[c0+1], b2 = bias[c0+2], b3 = bias[c0+3];
#pragma unroll
  for (int j = 0; j < 4; ++j) {
    int row = rblk + r0 + j;
    // round to fp16 so stored X and proj input are identical
    float v0 = h2f(fmaxf(acc[j][0] + b0, 0.f));
    float v1 = h2f(fmaxf(acc[j][1] + b1, 0.f));
    float v2 = h2f(fmaxf(acc[j][2] + b2, 0.f));
    float v3 = h2f(fmaxf(acc[j][3] + b3, 0.f));
    if (row < M)
      store_h4(&X[(size_t)row * 64 + c0], v0, v1, v2, v3);
    float sx = rsum16(v0*v0 + v1*v1 + v2*v2 + v3*v3);
    float norm = fmaxf(sqrtf(sx), MINNORM_F);
    float s = ((norm > MAXNORM_F) ? (MAXNORM_F / norm) : 1.0f) * SCALING_F;
    if (row < M)
      *(float4*)&Z[(size_t)row * 64 + c0] = make_float4(v0*s, v1*s, v2*s, v3*s);
  }
}

// ---------------------------------------------------------------------------
// K1 (64-row tile): h = relu((x[r] + sum_nb x[nb]) @ W1 + b1), fp16 x and h,
// fused BN statistics (computed from the fp16-rounded stored h).
// ---------------------------------------------------------------------------
__global__ __launch_bounds__(256) void k_layer1(
    const __half* __restrict__ x, const int* __restrict__ rowptr,
    const int* __restrict__ csr, const float* __restrict__ B,
    const float* __restrict__ bias, __half* __restrict__ h,
    float* __restrict__ gstat, int M)
{
  __shared__ float As[64][65];
  __shared__ float Bs[64][64];
  const int tid  = threadIdx.x;
  const int c0   = (tid & 15) * 4;
  const int r0   = (tid >> 4) * 4;
  const int rblk = blockIdx.x * 64;
  const int wv   = tid >> 6;
  const int lane = tid & 63;

#pragma unroll
  for (int j = 0; j < 4; ++j) {
    int f = j * 256 + tid;
    int bk = f >> 4, bc = (f & 15) * 4;
    *(float4*)&Bs[bk][bc] = *(const float4*)&B[(size_t)bk * 64 + bc];
  }
  for (int rr = 0; rr < 16; ++rr) {
    int lr = wv * 16 + rr;
    int r  = rblk + lr;
    float acc = 0.f;
    if (r < M) {
      acc = __half2float(x[(size_t)r * 64 + lane]);
      int beg = rowptr[r], end = rowptr[r + 1];
      int j = beg;
      for (; j + 8 <= end; j += 8) {
        int n0 = csr[j+0], n1 = csr[j+1], n2 = csr[j+2], n3 = csr[j+3];
        int n4 = csr[j+4], n5 = csr[j+5], n6 = csr[j+6], n7 = csr[j+7];
        float v0 = __half2float(x[(size_t)n0*64+lane]);
        float v1 = __half2float(x[(size_t)n1*64+lane]);
        float v2 = __half2float(x[(size_t)n2*64+lane]);
        float v3 = __half2float(x[(size_t)n3*64+lane]);
        float v4 = __half2float(x[(size_t)n4*64+lane]);
        float v5 = __half2float(x[(size_t)n5*64+lane]);
        float v6 = __half2float(x[(size_t)n6*64+lane]);
        float v7 = __half2float(x[(size_t)n7*64+lane]);
        acc += ((v0+v1)+(v2+v3)) + ((v4+v5)+(v6+v7));
      }
      if (j + 4 <= end) {
        int n0 = csr[j+0], n1 = csr[j+1], n2 = csr[j+2], n3 = csr[j+3];
        float v0 = __half2float(x[(size_t)n0*64+lane]);
        float v1 = __half2float(x[(size_t)n1*64+lane]);
        float v2 = __half2float(x[(size_t)n2*64+lane]);
        float v3 = __half2float(x[(size_t)n3*64+lane]);
        acc += (v0+v1)+(v2+v3);
        j += 4;
      }
      for (; j < end; ++j) acc += __half2float(x[(size_t)csr[j]*64+lane]);
    }
    As[lr][lane] = acc;
  }
  __syncthreads();

  float acc[4][4] = {{0.f,0.f,0.f,0.f},{0.f,0.f,0.f,0.f},
                     {0.f,0.f,0.f,0.f},{0.f,0.f,0.f,0.f}};
#pragma unroll 16
  for (int k = 0; k < 64; ++k) {
    float4 b4 = *(float4*)&Bs[k][c0];
    float a0 = As[r0 + 0][k], a1 = As[r0 + 1][k];
    float a2 = As[r0 + 2][k], a3 = As[r0 + 3][k];
    acc[0][0] = fmaf(a0,b4.x,acc[0][0]); acc[0][1] = fmaf(a0,b4.y,acc[0][1]);
    acc[0][2] = fmaf(a0,b4.z,acc[0][2]); acc[0][3] = fmaf(a0,b4.w,acc[0][3]);
    acc[1][0] = fmaf(a1,b4.x,acc[1][0]); acc[1][1] = fmaf(a1,b4.y,acc[1][1]);
    acc[1][2] = fmaf(a1,b4.z,acc[1][2]); acc[1][3] = fmaf(a1,b4.w,acc[1][3]);
    acc[2][0] = fmaf(a2,b4.x,acc[2][0]); acc[2][1] = fmaf(a2,b4.y,acc[2][1]);
    acc[2][2] = fmaf(a2,b4.z,acc[2][2]); acc[2][3] = fmaf(a2,b4.w,acc[2][3]);
    acc[3][0] = fmaf(a3,b4.x,acc[3][0]); acc[3][1] = fmaf(a3,b4.y,acc[3][1]);
    acc[3][2] = fmaf(a3,b4.z,acc[3][2]); acc[3][3] = fmaf(a3,b4.w,acc[3][3]);
  }
  __syncthreads();   // Bs dead after this; reused as stats scratch

  float b0 = bias[c0+0], b1 = bias[c0+1], b2 = bias[c0+2], b3 = bias[c0+3];
  float s[4] = {0.f,0.f,0.f,0.f}, q[4] = {0.f,0.f,0.f,0.f};
#pragma unroll
  for (int j = 0; j < 4; ++j) {
    int row = rblk + r0 + j;
    if (row >= M) continue;
    // fp16-round first so stats match the stored h exactly
    float v0 = h2f(fmaxf(acc[j][0] + b0, 0.f));
    float v1 = h2f(fmaxf(acc[j][1] + b1, 0.f));
    float v2 = h2f(fmaxf(acc[j][2] + b2, 0.f));
    float v3 = h2f(fmaxf(acc[j][3] + b3, 0.f));
    s[0] += v0; s[1] += v1; s[2] += v2; s[3] += v3;
    q[0] += v0*v0; q[1] += v1*v1; q[2] += v2*v2; q[3] += v3*v3;
    store_h4(&h[(size_t)row * 64 + c0], v0, v1, v2, v3);
  }
  {
    float* st = (float*)Bs;           // [0:1024) sums, [1024:2048) sumsq
    int g = tid >> 4;
#pragma unroll
    for (int i = 0; i < 4; ++i) {
      st[g * 64 + c0 + i]        = s[i];
      st[1024 + g * 64 + c0 + i] = q[i];
    }
    __syncthreads();
    if (tid < 64) {
      float a = 0.f, b = 0.f;
#pragma unroll
      for (int g2 = 0; g2 < 16; ++g2) {
        a += st[g2 * 64 + tid];
        b += st[1024 + g2 * 64 + tid];
      }
      atomicAdd(&gstat[tid], a);
      atomicAdd(&gstat[64 + tid], b);
    }
  }
}

// ---------------------------------------------------------------------------
// K2 (64-row tile): xn = relu(BN(h) @ W2 + b2), col63 = 0; fused hyp epilogue.
// h read fp16, X written fp16, Z buffers fp32. BN scale/shift from gstat.
// If Zn != null: write X and Zn. Else (last layer): logmap0 + pool.
// ---------------------------------------------------------------------------
__global__ __launch_bounds__(256) void k_layer2(
    const __half* __restrict__ A, const float* __restrict__ B,
    const float* __restrict__ bias,
    const float* __restrict__ gstat, const float* __restrict__ gamma,
    const float* __restrict__ beta,
    __half* __restrict__ X,
    const float* __restrict__ Zc, const float* Zp, float* Zn,
    const int* __restrict__ batch, float* __restrict__ pool, int M)
{
  __shared__ float As[64][65];
  __shared__ float Bs[64][64];
  __shared__ float scl_s[64], shf_s[64];
  const int tid  = threadIdx.x;
  const int c0   = (tid & 15) * 4;
  const int r0   = (tid >> 4) * 4;
  const int rblk = blockIdx.x * 64;

  if (tid < 64) {
    float mu  = gstat[tid] / (float)M;
    float var = gstat[64 + tid] / (float)M - mu * mu;
    float sv  = gamma[tid] / sqrtf(var + BN_EPS_F);
    scl_s[tid] = sv;
    shf_s[tid] = beta[tid] - mu * sv;
  }
  __syncthreads();

#pragma unroll
  for (int j = 0; j < 4; ++j) {
    int f = j * 256 + tid;
    int bk = f >> 4, bc = (f & 15) * 4;
    *(float4*)&Bs[bk][bc] = *(const float4*)&B[(size_t)bk * 64 + bc];
  }
#pragma unroll
  for (int j = 0; j < 4; ++j) {
    int f = j * 256 + tid;
    int ar = f >> 4, ac = (f & 15) * 4;
    int row = rblk + ar;
    float a0 = 0.f, a1 = 0.f, a2 = 0.f, a3 = 0.f;
    if (row < M) load_h4(&A[(size_t)row * 64 + ac], a0, a1, a2, a3);
    As[ar][ac + 0] = fmaf(a0, scl_s[ac+0], shf_s[ac+0]);
    As[ar][ac + 1] = fmaf(a1, scl_s[ac+1], shf_s[ac+1]);
    As[ar][ac + 2] = fmaf(a2, scl_s[ac+2], shf_s[ac+2]);
    As[ar][ac + 3] = fmaf(a3, scl_s[ac+3], shf_s[ac+3]);
  }

  // prefetch zc/zp so they're in flight during staging barrier + FMA loop
  float4 zc4[4], zp4[4];
#pragma unroll
  for (int j = 0; j < 4; ++j) {
    int row = rblk + r0 + j;
    zc4[j] = make_float4(0.f, 0.f, 0.f, 0.f);
    zp4[j] = make_float4(0.f, 0.f, 0.f, 0.f);
    if (row < M) zc4[j] = *(const float4*)&Zc[(size_t)row * 64 + c0];
    if (row < M && Zp != nullptr) zp4[j] = *(const float4*)&Zp[(size_t)row * 64 + c0];
  }
  __syncthreads();

  float acc[4][4] = {{0.f,0.f,0.f,0.f},{0.f,0.f,0.f,0.f},
                     {0.f,0.f,0.f,0.f},{0.f,0.f,0.f,0.f}};
#pragma unroll 16
  for (int k = 0; k < 64; ++k) {
    float4 b4 = *(float4*)&Bs[k][c0];
    float a0 = As[r0 + 0][k], a1 = As[r0 + 1][k];
    float a2 = As[r0 + 2][k], a3 = As[r0 + 3][k];
    acc[0][0] = fmaf(a0,b4.x,acc[0][0]); acc[0][1] = fmaf(a0,b4.y,acc[0][1]);
    acc[0][2] = fmaf(a0,b4.z,acc[0][2]); acc[0][3] = fmaf(a0,b4.w,acc[0][3]);
    acc[1][0] = fmaf(a1,b4.x,acc[1][0]); acc[1][1] = fmaf(a1,b4.y,acc[1][1]);
    acc[1][2] = fmaf(a1,b4.z,acc[1][2]); acc[1][3] = fmaf(a1,b4.w,acc[1][3]);
    acc[2][0] = fmaf(a2,b4.x,acc[2][0]); acc[2][1] = fmaf(a2,b4.y,acc[2][1]);
    acc[2][2] = fmaf(a2,b4.z,acc[2][2]); acc[2][3] = fmaf(a2,b4.w,acc[2][3]);
    acc[3][0] = fmaf(a3,b4.x,acc[3][0]); acc[3][1] = fmaf(a3,b4.y,acc[3][1]);
    acc[3][2] = fmaf(a3,b4.z,acc[3][2]); acc[3][3] = fmaf(a3,b4.w,acc[3][3]);
  }

  float b0 = bias[c0+0], b1 = bias[c0+1], b2 = bias[c0+2], b3 = bias[c0+3];

#pragma unroll
  for (int j = 0; j < 4; ++j) {
    int row = rblk + r0 + j;
    bool valid = (row < M);
    // fp16-round so stored X and the hyperbolic ch use identical values
    float xv[4];
    xv[0] = h2f(fmaxf(acc[j][0] + b0, 0.f));
    xv[1] = h2f(fmaxf(acc[j][1] + b1, 0.f));
    xv[2] = h2f(fmaxf(acc[j][2] + b2, 0.f));
    xv[3] = h2f(fmaxf(acc[j][3] + b3, 0.f));
    if (c0 == 60) xv[3] = 0.f;     // x[:, -1] = 0
    if (valid && X != nullptr)
      store_h4(&X[(size_t)row * 64 + c0], xv[0], xv[1], xv[2], xv[3]);

    float zcv[4] = {zc4[j].x, zc4[j].y, zc4[j].z, zc4[j].w};
    float zpv[4] = {zp4[j].x, zp4[j].y, zp4[j].z, zp4[j].w};

    // six independent dot-product partials
    float p1 = xv[0]*xv[0] + xv[1]*xv[1] + xv[2]*xv[2] + xv[3]*xv[3];   // Σxv²
    float p2 = zcv[0]*zcv[0]+zcv[1]*zcv[1]+zcv[2]*zcv[2]+zcv[3]*zcv[3]; // Σzc²
    float p3 = zpv[0]*zpv[0]+zpv[1]*zpv[1]+zpv[2]*zpv[2]+zpv[3]*zpv[3]; // Σzp²
    float p4 = zpv[0]*zcv[0]+zpv[1]*zcv[1]+zpv[2]*zcv[2]+zpv[3]*zcv[3]; // Σzp·zc
    float p5 = zpv[0]*xv[0]+zpv[1]*xv[1]+zpv[2]*xv[2]+zpv[3]*xv[3];     // Σzp·xv
    float p6 = zcv[0]*xv[0]+zcv[1]*xv[1]+zcv[2]*xv[2]+zcv[3]*xv[3];     // Σzc·xv
    rsum16x6(p1, p2, p3, p4, p5, p6);
    float zc63 = __shfl(zcv[3], 15, 16);   // element 63 of this row
    float zp63 = __shfl(zpv[3], 15, 16);

    // ---- scalar chain (uniform within the 16-lane group) ----
    float nzc2 = fmaxf(p2, MINNORM_F);
    float icz  = 1.0f / nzc2;
    float na2  = p2 * icz * icz;           // Σa²
    float r2   = na2 - 1.0f;
    float a63  = zc63 * icz;

    float sxn = fmaxf(sqrtf(p1), MINNORM_F);
    float sc  = ((sxn > MAXNORM_F) ? (MAXNORM_F / sxn) : 1.0f) * SCALING_F;
    float Sch2   = sc * sc * p1;           // Σch²   (ch63 = 0)
    float Szp_a  = p4 * icz;               // Σzp·a
    float Sa_ch  = sc * p6 * icz;          // Σa·ch
    float Szp_ch = sc * p5;                // Σzp·ch
    float Su_a   = Szp_a - na2;            // Σ(zp−a)·a
    float Su2    = p3 - 2.0f * Szp_a + na2;
    float nu2    = fmaxf(Su2, MINNORM_F);
    float t1     = r2 / nu2;
    float Szp22  = fmaxf(t1*t1*Su2 + 2.0f*t1*Su_a + na2, 0.0f);  // Σzp2²
    float npn    = fmaxf(sqrtf(Szp22), MINNORM_F);
    float ipn    = 1.0f / npn;
    float zp2_63 = t1 * (zp63 - a63) + a63;
    float Szp2ch = t1 * (Szp_ch - Sa_ch) + Sa_ch;
    float rdc    = -ipn * Szp2ch;          // Σr·ch  (q·ch = ch63 = 0)
    float rdr    = 1.0f - 2.0f*ipn*zp2_63 + ipn*ipn*Szp22;       // Σr·r
    float m2     = 2.0f * rdc / rdr;
    float Szp2a  = t1 * Su_a + na2;        // Σzp2·a
    float Srr_a  = a63 - ipn * Szp2a;      // Σr·a
    float Sc2a   = Sa_ch - m2 * Srr_a;     // Σc2·a
    float Sc22   = Sch2 - 2.0f*m2*rdc + m2*m2*rdr;               // Σc2²
    float Sc2ma  = Sc22 - 2.0f*Sc2a + na2; // Σ(c2−a)²
    float nu22   = fmaxf(Sc2ma, MINNORM_F);
    float t2     = r2 / nu22;

    // ---- per-lane vector tail ----
    float zn[4];
#pragma unroll
    for (int i = 0; i < 4; ++i) {
      float ai  = zcv[i] * icz;
      float zp2 = t1 * (zpv[i] - ai) + ai;
      float rri = (((c0 + i) == 63) ? 1.0f : 0.0f) - ipn * zp2;
      float c2  = sc * xv[i] - m2 * rri;
      zn[i]     = t2 * (c2 - ai) + ai;
    }

    if (Zn != nullptr) {
      if (valid)
        *(float4*)&Zn[(size_t)row * 64 + c0] = make_float4(zn[0],zn[1],zn[2],zn[3]);
    } else {
      float Szn2 = fmaxf(t2*t2*Sc2ma + 2.0f*t2*(Sc2a - na2) + na2, 0.0f);
      float yn  = fmaxf(sqrtf(Szn2), MINNORM_F);
      float t   = fminf(yn, 1.0f);
      float ath = 0.5f * logf((1.0f + t) / (1.0f - t));
      float wsc = ath / yn;
      if (valid) {
        int b = batch[row];
        float* p = &pool[(size_t)b * 64 + c0];
        atomicAdd(p + 0, zn[0] * wsc);
        atomicAdd(p + 1, zn[1] * wsc);
        atomicAdd(p + 2, zn[2] * wsc);
        atomicAdd(p + 3, zn[3] * wsc);
      }
    }
  }
}

// ---------------------------------------------------------------------------
// CSR build
// ---------------------------------------------------------------------------
__global__ __launch_bounds__(256) void k_deg(const int* __restrict__ dst, int E, int* deg) {
  int i0 = (blockIdx.x * 256 + threadIdx.x) * 4;
  if (i0 + 4 <= E) {
    int d0 = dst[i0], d1 = dst[i0+1], d2 = dst[i0+2], d3 = dst[i0+3];
    atomicAdd(&deg[d0], 1);
    atomicAdd(&deg[d1], 1);
    atomicAdd(&deg[d2], 1);
    atomicAdd(&deg[d3], 1);
  } else {
    for (int i = i0; i < E; ++i) atomicAdd(&deg[dst[i]], 1);
  }
}

__global__ __launch_bounds__(256) void k_scan1(const int* __restrict__ deg, int N,
                                               int* rowptr, int* bsum) {
  __shared__ int s[256];
  int t = threadIdx.x;
  int i = blockIdx.x * 256 + t;
  int v = (i < N) ? deg[i] : 0;
  s[t] = v;
  __syncthreads();
  for (int d = 1; d < 256; d <<= 1) {
    int add = (t >= d) ? s[t - d] : 0;
    __syncthreads();
    s[t] += add;
    __syncthreads();
  }
  if (i < N) rowptr[i] = s[t] - v;
  if (t == 255) bsum[blockIdx.x] = s[255];
}

__global__ __launch_bounds__(256) void k_scan2(const int* __restrict__ bsum, int NB, int* boff) {
  __shared__ int s[256];
  int t = threadIdx.x;
  int v = (t < NB) ? bsum[t] : 0;
  s[t] = v;
  __syncthreads();
  for (int d = 1; d < 256; d <<= 1) {
    int add = (t >= d) ? s[t - d] : 0;
    __syncthreads();
    s[t] += add;
    __syncthreads();
  }
  boff[t] = s[t] - v;
}

__global__ __launch_bounds__(256) void k_scan3(int* rowptr, const int* __restrict__ boff,
                                               int* cursor, int N, int E) {
  int i = blockIdx.x * 256 + threadIdx.x;
  if (i < N) {
    int v = rowptr[i] + boff[blockIdx.x];
    rowptr[i] = v;
    cursor[i] = v;
  }
  if (i == 0) rowptr[N] = E;
}

__global__ __launch_bounds__(256) void k_fill(const int* __restrict__ src,
                                              const int* __restrict__ dst, int E,
                                              int* cursor, int* __restrict__ csr) {
  int i0 = (blockIdx.x * 256 + threadIdx.x) * 4;
  if (i0 + 4 <= E) {
    int d0 = dst[i0], d1 = dst[i0+1], d2 = dst[i0+2], d3 = dst[i0+3];
    int s0 = src[i0], s1 = src[i0+1], s2 = src[i0+2], s3 = src[i0+3];
    int p0 = atomicAdd(&cursor[d0], 1);
    int p1 = atomicAdd(&cursor[d1], 1);
    int p2 = atomicAdd(&cursor[d2], 1);
    int p3 = atomicAdd(&cursor[d3], 1);
    csr[p0] = s0;
    csr[p1] = s1;
    csr[p2] = s2;
    csr[p3] = s3;
  } else {
    for (int i = i0; i < E; ++i) {
      int p = atomicAdd(&cursor[dst[i]], 1);
      csr[p] = src[i];
    }
  }
}

// ---------------------------------------------------------------------------
// Per-graph MLP head + log_softmax
// ---------------------------------------------------------------------------
__global__ __launch_bounds__(128) void k_mlp(const float* __restrict__ pool,
                                             const float* __restrict__ fc1W, const float* __restrict__ fc1b,
                                             const float* __restrict__ fc2W, const float* __restrict__ fc2b,
                                             const float* __restrict__ fc3W, const float* __restrict__ fc3b,
                                             float* __restrict__ out) {
  __shared__ float p[64], o1[128], o2[64], lg[10], red[2];
  int g = blockIdx.x, t = threadIdx.x;
  if (t < 64) p[t] = pool[(size_t)g * 64 + t];
  __syncthreads();
  {
    float a = fc1b[t];
    for (int k = 0; k < 64; ++k) a = fmaf(p[k], fc1W[k * 128 + t], a);
    o1[t] = fmaxf(a, 0.f);
  }
  __syncthreads();
  if (t < 64) {
    float a = fc2b[t];
    for (int k = 0; k < 128; ++k) a = fmaf(o1[k], fc2W[k * 64 + t], a);
    o2[t] = fmaxf(a, 0.f);
  }
  __syncthreads();
  if (t < 10) {
    float a = fc3b[t];
    for (int k = 0; k < 64; ++k) a = fmaf(o2[k], fc3W[k * 10 + t], a);
    lg[t] = a;
  }
  __syncthreads();
  if (t == 0) {
    float mx = lg[0];
    for (int j = 1; j < 10; ++j) mx = fmaxf(mx, lg[j]);
    float s = 0.f;
    for (int j = 0; j < 10; ++j) s += expf(lg[j] - mx);
    red[0] = mx;
    red[1] = logf(s);
  }
  __syncthreads();
  if (t < 10) out[(size_t)g * 10 + t] = lg[t] - red[0] - red[1];
}

// ---------------------------------------------------------------------------
extern "C" void kernel_launch(void* const* d_in, const int* in_sizes, int n_in,
                              void* d_out, int out_size, void* d_ws, size_t ws_size,
                              hipStream_t stream) {
  const float* x_in  = (const float*)d_in[0];
  const int*   ei    = (const int*)d_in[1];
  const int*   batch = (const int*)d_in[2];
  const float* W0    = (const float*)d_in[3];
  const float* b0    = (const float*)d_in[4];
  const float* cW1   = (const float*)d_in[5];
  const float* cb1   = (const float*)d_in[6];
  const float* gamma = (const float*)d_in[7];
  const float* beta  = (const float*)d_in[8];
  const float* cW2   = (const float*)d_in[9];
  const float* cb2   = (const float*)d_in[10];
  const float* fc1W  = (const float*)d_in[11];
  const float* fc1b  = (const float*)d_in[12];
  const float* fc2W  = (const float*)d_in[13];
  const float* fc2b  = (const float*)d_in[14];
  const float* fc3W  = (const float*)d_in[15];
  const float* fc3b  = (const float*)d_in[16];
  float* out = (float*)d_out;

  const int N = in_sizes[0] / 128;
  const int E = in_sizes[1] / 2;
  const int L = in_sizes[5] / (64 * 64);
  const int G = out_size / 10;
  const int* src = ei;
  const int* dst = ei + E;

  char* ws = (char*)d_ws;
  size_t off = 0;
  auto alloc = [&](size_t bytes) -> char* {
    char* p = ws + off;
    off += (bytes + 255) & ~(size_t)255;
    return p;
  };
  __half* X  = (__half*)alloc((size_t)N * 64 * 2);
  __half* Bf = (__half*)alloc((size_t)N * 64 * 2);
  float* zb0  = (float*)alloc((size_t)N * 64 * 4);
  float* zb1  = (float*)alloc((size_t)N * 64 * 4);
  float* zb2  = (float*)alloc((size_t)N * 64 * 4);
  // ---- zeroed region: deg, pool, gstatAll (contiguous) ----
  int*   deg  = (int*)alloc((size_t)N * 4);
  float* pool = (float*)alloc((size_t)G * 64 * 4);
  float* gstatAll = (float*)alloc((size_t)3 * 128 * 4);
  char*  zero_end = ws + off;
  // ---------------------------------------------------------
  int*   rowptr = (int*)alloc((size_t)(N + 1) * 4);
  int*   cursor = (int*)alloc((size_t)N * 4);
  int*   csr    = (int*)alloc((size_t)E * 4);
  int*   bsum   = (int*)alloc(256 * 4);
  int*   boff   = (int*)alloc(256 * 4);
  float* zbuf[3] = {zb0, zb1, zb2};

  hipMemsetAsync(deg, 0, (size_t)(zero_end - (char*)deg), stream);

  const int mmGrid    = (N + 63) / 64;
  const int edge4Grid = (E / 4 + 255) / 256 + 1;

  // X = relu(x @ W0 + b0) (fp16); Z1 = SCALING*project(X) (fp32)
  k_mm0<<<mmGrid, 256, 0, stream>>>(x_in, W0, b0, X, zbuf[0], N, 128);

  // CSR build
  k_deg<<<edge4Grid, 256, 0, stream>>>(dst, E, deg);
  const int NB = (N + 255) / 256;
  k_scan1<<<NB, 256, 0, stream>>>(deg, N, rowptr, bsum);
  k_scan2<<<1, 256, 0, stream>>>(bsum, NB, boff);
  k_scan3<<<NB, 256, 0, stream>>>(rowptr, boff, cursor, N, E);
  k_fill<<<edge4Grid, 256, 0, stream>>>(src, dst, E, cursor, csr);

  for (int i = 0; i < L; ++i) {
    float* gstat = gstatAll + (size_t)i * 128;
    const int last = (i == L - 1);
    k_layer1<<<mmGrid, 256, 0, stream>>>(X, rowptr, csr,
                                         cW1 + (size_t)i * 64 * 64, cb1 + i * 64,
                                         Bf, gstat, N);
    k_layer2<<<mmGrid, 256, 0, stream>>>(Bf, cW2 + (size_t)i * 64 * 64, cb2 + i * 64,
                                         gstat, gamma + i * 64, beta + i * 64,
                                         last ? nullptr : X,
                                         zbuf[i],
                                         (i == 0) ? nullptr : zbuf[i - 1],
                                         last ? nullptr : zbuf[i + 1],
                                         batch, pool, N);
  }

  k_mlp<<<G, 128, 0, stream>>>(pool, fc1W, fc1b, fc2W, fc2b, fc3W, fc3b, out);
}